// Round 4
// baseline (838.911 us; speedup 1.0000x reference)
//
#include <hip/hip_runtime.h>

#define NODES 100000
#define EDGES 100000
#define NNZV  1600000
#define FB    16            // blocks per range-group (hist/fill), 1024 threads each
#define NCH   98            // scan chunks per array: ceil(100000/1024)

typedef unsigned short u16;
__device__ __forceinline__ float b2f(u16 h) {
  union { unsigned u; float f; } c; c.u = ((unsigned)h) << 16; return c.f;
}
__device__ __forceinline__ u16 f2b(float f) {
  union { unsigned u; float f; } c; c.f = f;
  unsigned u = c.u + 0x7FFF + ((c.u >> 16) & 1);   // round-to-nearest-even
  return (u16)(u >> 16);
}

// ================= CSR build: range-partitioned, NT streaming reads =================
__global__ __launch_bounds__(1024) void hist_kernel(const int* __restrict__ nidx,
                                                    const int* __restrict__ eidx,
                                                    int* __restrict__ cnt_v, int* __restrict__ cnt_e) {
  const int grp = blockIdx.x & 15;
  const int blk = blockIdx.x >> 4;
  const bool is_e = grp < 8;
  const int lo = (grp & 7) * (EDGES / 8), hi = lo + (EDGES / 8);
  const int chunk = (NNZV + FB - 1) / FB;
  const int j1 = min(blk * chunk + chunk, NNZV);
  const int* __restrict__ key = is_e ? eidx : nidx;
  int* __restrict__ cnt = is_e ? cnt_e : cnt_v;
  for (int j = blk * chunk + threadIdx.x; j < j1; j += 1024) {
    int k = __builtin_nontemporal_load(key + j);
    if (k >= lo && k < hi) atomicAdd(&cnt[k], 1);
  }
}

__global__ __launch_bounds__(1024) void fill_kernel(const int* __restrict__ nidx,
                                                    const int* __restrict__ eidx,
                                                    int* __restrict__ cur_v, int* __restrict__ cur_e,
                                                    int* __restrict__ col_v, int* __restrict__ col_e) {
  const int grp = blockIdx.x & 15;
  const int blk = blockIdx.x >> 4;
  const bool is_e = grp < 8;
  const int lo = (grp & 7) * (EDGES / 8), hi = lo + (EDGES / 8);
  const int chunk = (NNZV + FB - 1) / FB;
  const int j1 = min(blk * chunk + chunk, NNZV);
  const int* __restrict__ key = is_e ? eidx : nidx;
  const int* __restrict__ val = is_e ? nidx : eidx;
  int* __restrict__ cur = is_e ? cur_e : cur_v;
  int* __restrict__ col = is_e ? col_e : col_v;
  for (int j = blk * chunk + threadIdx.x; j < j1; j += 1024) {
    int k = __builtin_nontemporal_load(key + j);
    if (k >= lo && k < hi) {
      int v = __builtin_nontemporal_load(val + j);
      int p = atomicAdd(&cur[k], 1);
      col[p] = v;
    }
  }
}

// ================= 3-phase exclusive scan over cur_e / cur_v =================
__global__ __launch_bounds__(256) void scan_phase1(const int* __restrict__ cur_e,
                                                   const int* __restrict__ cur_v,
                                                   int* __restrict__ part) {
  const int b = blockIdx.x;
  const bool is_v = b >= NCH;
  const int* src = is_v ? cur_v : cur_e;
  const int base = (is_v ? b - NCH : b) * 1024;
  const int tid = threadIdx.x, lane = tid & 63, wid = tid >> 6;
  int s = 0;
  #pragma unroll
  for (int i = 0; i < 4; i++) {
    int idx = base + tid * 4 + i;
    if (idx < EDGES) s += src[idx];
  }
  #pragma unroll
  for (int d = 1; d < 64; d <<= 1) s += __shfl_xor(s, d);
  __shared__ int ws[4];
  if (lane == 0) ws[wid] = s;
  __syncthreads();
  if (tid == 0) part[b] = ws[0] + ws[1] + ws[2] + ws[3];
}

__global__ void scan_phase2(int* __restrict__ part, int* __restrict__ off_e, int* __restrict__ off_v) {
  if (threadIdx.x == 0) {
    int a = 0;
    for (int i = 0; i < NCH; i++) { int t = part[i]; part[i] = a; a += t; }
    off_e[EDGES] = a;
    int c = 0;
    for (int i = NCH; i < 2 * NCH; i++) { int t = part[i]; part[i] = c; c += t; }
    off_v[NODES] = c;
  }
}

__global__ __launch_bounds__(256) void scan_phase3(const int* __restrict__ part,
                                                   int* __restrict__ cur_e, int* __restrict__ off_e,
                                                   int* __restrict__ cur_v, int* __restrict__ off_v) {
  const int b = blockIdx.x;
  const bool is_v = b >= NCH;
  int* __restrict__ cnt = is_v ? cur_v : cur_e;
  int* __restrict__ off = is_v ? off_v : off_e;
  const int base = (is_v ? b - NCH : b) * 1024;
  const int tid = threadIdx.x, lane = tid & 63, wid = tid >> 6;
  int vals[4]; int s = 0;
  #pragma unroll
  for (int i = 0; i < 4; i++) {
    int idx = base + tid * 4 + i;
    vals[i] = (idx < EDGES) ? cnt[idx] : 0;
    s += vals[i];
  }
  int x = s;
  #pragma unroll
  for (int d = 1; d < 64; d <<= 1) { int t = __shfl_up(x, d); if (lane >= d) x += t; }
  __shared__ int ws[4];
  if (lane == 63) ws[wid] = x;
  __syncthreads();
  int wbase = 0;
  for (int k = 0; k < wid; k++) wbase += ws[k];
  int excl = part[b] + wbase + x - s;
  #pragma unroll
  for (int i = 0; i < 4; i++) {
    int idx = base + tid * 4 + i;
    if (idx < EDGES) { off[idx] = excl; cnt[idx] = excl; }
    excl += vals[i];
  }
}

// ======= GEMM: Y[M,N](bf16) = X[M,128] @ W[128,N];  X is f32 (XBF=0) or bf16 (XBF=1) =======
template<int N, bool XBF>
__global__ __launch_bounds__(256) void gemm_kernel(const void* __restrict__ Xv,
                                                   const float* __restrict__ W,
                                                   u16* __restrict__ Y, int M) {
  __shared__ float sW[128 * N];
  __shared__ float sX[4][8 * 128];
  const int tid = threadIdx.x, wave = tid >> 6, lane = tid & 63;
  for (int i = tid * 4; i < 128 * N; i += 1024)
    *(float4*)(sW + i) = *(const float4*)(W + i);
  __syncthreads();
  constexpr int CPL = N / 64;
  for (int chunk = blockIdx.x * 32; chunk < M; chunk += gridDim.x * 32) {
    const int row0 = chunk + wave * 8;
    if constexpr (XBF) {
      const u16* src = (const u16*)Xv + (size_t)row0 * 128;
      #pragma unroll
      for (int it = 0; it < 4; it++) {
        ushort4 v = *(const ushort4*)(src + (size_t)(lane + 64 * it) * 4);
        float4 f = make_float4(b2f(v.x), b2f(v.y), b2f(v.z), b2f(v.w));
        ((float4*)sX[wave])[lane + 64 * it] = f;
      }
    } else {
      const float4* src = (const float4*)((const float*)Xv + (size_t)row0 * 128);
      #pragma unroll
      for (int i = 0; i < 4; i++) ((float4*)sX[wave])[lane + 64 * i] = src[lane + 64 * i];
    }
    float acc[8][CPL];
    #pragma unroll
    for (int r = 0; r < 8; r++)
      #pragma unroll
      for (int c = 0; c < CPL; c++) acc[r][c] = 0.f;
    const float* xw = sX[wave];
    #pragma unroll 2
    for (int k = 0; k < 128; k += 4) {
      float4 xr[8];
      #pragma unroll
      for (int r = 0; r < 8; r++) xr[r] = *(const float4*)(xw + r * 128 + k);
      #pragma unroll
      for (int kk = 0; kk < 4; kk++) {
        #pragma unroll
        for (int c = 0; c < CPL; c++) {
          float w = sW[(k + kk) * N + lane + 64 * c];
          #pragma unroll
          for (int r = 0; r < 8; r++)
            acc[r][c] = fmaf(((const float*)&xr[r])[kk], w, acc[r][c]);
        }
      }
    }
    #pragma unroll
    for (int r = 0; r < 8; r++)
      #pragma unroll
      for (int c = 0; c < CPL; c++)
        Y[(size_t)(row0 + r) * N + lane + 64 * c] = f2b(acc[r][c]);
  }
}

// ========== gather node->edge (bf16->bf16): dst[e] = (1/deg_e) * sum src[v] ==========
template<int F>
__global__ __launch_bounds__(256) void gather_n2e(const int* __restrict__ off, const int* __restrict__ col,
                                                  const u16* __restrict__ src, u16* __restrict__ dst,
                                                  int nrows) {
  const int row = blockIdx.x * 4 + (threadIdx.x >> 6);
  if (row >= nrows) return;
  const int lane = threadIdx.x & 63;
  const int s0 = off[row], s1 = off[row + 1];
  float a0 = 0.f, a1 = 0.f, b0 = 0.f, b1 = 0.f;
  int k = s0;
  for (; k + 1 < s1; k += 2) {
    int c0 = col[k], c1 = col[k + 1];
    if constexpr (F == 128) {
      ushort2 u0 = *(const ushort2*)(src + (size_t)c0 * F + lane * 2);
      ushort2 u1 = *(const ushort2*)(src + (size_t)c1 * F + lane * 2);
      a0 += b2f(u0.x); a1 += b2f(u0.y); b0 += b2f(u1.x); b1 += b2f(u1.y);
    } else {
      a0 += b2f(src[(size_t)c0 * F + lane]);
      b0 += b2f(src[(size_t)c1 * F + lane]);
    }
  }
  if (k < s1) {
    int c0 = col[k];
    if constexpr (F == 128) {
      ushort2 u0 = *(const ushort2*)(src + (size_t)c0 * F + lane * 2);
      a0 += b2f(u0.x); a1 += b2f(u0.y);
    } else {
      a0 += b2f(src[(size_t)c0 * F + lane]);
    }
  }
  const float sc = (s1 > s0) ? 1.0f / (float)(s1 - s0) : 0.f;
  if constexpr (F == 128) {
    ushort2 o; o.x = f2b((a0 + b0) * sc); o.y = f2b((a1 + b1) * sc);
    *(ushort2*)(dst + (size_t)row * F + lane * 2) = o;
  } else {
    dst[(size_t)row * F + lane] = f2b((a0 + b0) * sc);
  }
}

// == gather edge->node + bias (+relu): out[v] = [relu]((1/deg_v)*sum src[e] + b); dst bf16 or f32 ==
template<int F, bool RELU, bool DSTBF>
__global__ __launch_bounds__(256) void gather_e2n(const int* __restrict__ off, const int* __restrict__ col,
                                                  const u16* __restrict__ src, const float* __restrict__ bias,
                                                  void* __restrict__ dstv, int nrows) {
  const int row = blockIdx.x * 4 + (threadIdx.x >> 6);
  if (row >= nrows) return;
  const int lane = threadIdx.x & 63;
  const int s0 = off[row], s1 = off[row + 1];
  float a0 = 0.f, a1 = 0.f, b0 = 0.f, b1 = 0.f;
  int k = s0;
  for (; k + 1 < s1; k += 2) {
    int c0 = col[k], c1 = col[k + 1];
    if constexpr (F == 128) {
      ushort2 u0 = *(const ushort2*)(src + (size_t)c0 * F + lane * 2);
      ushort2 u1 = *(const ushort2*)(src + (size_t)c1 * F + lane * 2);
      a0 += b2f(u0.x); a1 += b2f(u0.y); b0 += b2f(u1.x); b1 += b2f(u1.y);
    } else {
      a0 += b2f(src[(size_t)c0 * F + lane]);
      b0 += b2f(src[(size_t)c1 * F + lane]);
    }
  }
  if (k < s1) {
    int c0 = col[k];
    if constexpr (F == 128) {
      ushort2 u0 = *(const ushort2*)(src + (size_t)c0 * F + lane * 2);
      a0 += b2f(u0.x); a1 += b2f(u0.y);
    } else {
      a0 += b2f(src[(size_t)c0 * F + lane]);
    }
  }
  const float sc = (s1 > s0) ? 1.0f / (float)(s1 - s0) : 0.f;
  if constexpr (F == 128) {
    float v0 = (a0 + b0) * sc + bias[lane * 2];
    float v1 = (a1 + b1) * sc + bias[lane * 2 + 1];
    if (RELU) { v0 = fmaxf(v0, 0.f); v1 = fmaxf(v1, 0.f); }
    if constexpr (DSTBF) {
      ushort2 o; o.x = f2b(v0); o.y = f2b(v1);
      *(ushort2*)((u16*)dstv + (size_t)row * F + lane * 2) = o;
    } else {
      *(float2*)((float*)dstv + (size_t)row * F + lane * 2) = make_float2(v0, v1);
    }
  } else {
    float v0 = (a0 + b0) * sc + bias[lane];
    if (RELU) v0 = fmaxf(v0, 0.f);
    if constexpr (DSTBF) ((u16*)dstv)[(size_t)row * F + lane] = f2b(v0);
    else ((float*)dstv)[(size_t)row * F + lane] = v0;
  }
}

extern "C" void kernel_launch(void* const* d_in, const int* in_sizes, int n_in,
                              void* d_out, int out_size, void* d_ws, size_t ws_size,
                              hipStream_t stream) {
  const float* x  = (const float*)d_in[0];
  const int*   hi = (const int*)d_in[1];
  const float* W1 = (const float*)d_in[2];
  const float* b1 = (const float*)d_in[3];
  const float* W2 = (const float*)d_in[4];
  const float* b2 = (const float*)d_in[5];
  float* out = (float*)d_out;
  const int* nidx = hi;             // row 0: node indices
  const int* eidx = hi + NNZV;      // row 1: edge indices

  char* w = (char*)d_ws;
  int* off_e = (int*)w;                            // 100001 ints
  int* off_v = (int*)(w + 524288);                 // 100001 ints
  int* cur_e = (int*)(w + 1048576);                // counts -> cursors
  int* cur_v = (int*)(w + 1572864);
  int* part  = (int*)(w + 2000000);                // 196 ints
  int* col_e = (int*)(w + 2097152);                // 1.6M ints
  int* col_v = (int*)(w + 8650752);                // 1.6M ints
  u16* bufH  = (u16*)(w + 16777216);               // 25.6 MB: h1, then h2, then m2e
  u16* bufM  = (u16*)(w + 16777216 + 25600000);    // 25.6 MB: m_e, then g2

  // ---- CSR build (both directions) ----
  hipMemsetAsync(w + 1048576, 0, 1048576, stream);     // zero cur_e + cur_v (+part)
  hist_kernel<<<16 * FB, 1024, 0, stream>>>(nidx, eidx, cur_v, cur_e);
  scan_phase1<<<2 * NCH, 256, 0, stream>>>(cur_e, cur_v, part);
  scan_phase2<<<1, 64, 0, stream>>>(part, off_e, off_v);
  scan_phase3<<<2 * NCH, 256, 0, stream>>>(part, cur_e, off_e, cur_v, off_v);
  fill_kernel<<<16 * FB, 1024, 0, stream>>>(nidx, eidx, cur_v, cur_e, col_v, col_e);

  // ---- conv1 (F=128) ----
  gemm_kernel<128, false><<<512, 256, 0, stream>>>(x, W1, bufH, NODES);            // h1(bf16)
  gather_n2e<128><<<(EDGES + 3) / 4, 256, 0, stream>>>(off_e, col_e, bufH, bufM, EDGES);   // m_e
  gather_e2n<128, true, true><<<(NODES + 3) / 4, 256, 0, stream>>>(off_v, col_v, bufM, b1, bufH, NODES); // h2

  // ---- conv2 (F=64) ----
  gemm_kernel<64, true><<<512, 256, 0, stream>>>(bufH, W2, bufM, NODES);           // g2(bf16)
  gather_n2e<64><<<(EDGES + 3) / 4, 256, 0, stream>>>(off_e, col_e, bufM, bufH, EDGES);    // m2e
  gather_e2n<64, false, false><<<(NODES + 3) / 4, 256, 0, stream>>>(off_v, col_v, bufH, b2, out, NODES);
}

// Round 5
// 465.083 us; speedup vs baseline: 1.8038x; 1.8038x over previous
//
#include <hip/hip_runtime.h>

#define NODES 100000
#define EDGES 100000
#define NNZV  1600000
#define NBK   196          // buckets per direction (512 rows each)
#define BKCAP 12288        // entry capacity per bucket (mean 8192, +45 sigma)
#define TILE  4096         // entries per partition block (256 thr x 16)
#define NTIL  391          // ceil(NNZV / TILE)

typedef unsigned short u16;
__device__ __forceinline__ float b2f(u16 h) {
  union { unsigned u; float f; } c; c.u = ((unsigned)h) << 16; return c.f;
}
__device__ __forceinline__ u16 f2b(float f) {
  union { unsigned u; float f; } c; c.f = f;
  unsigned u = c.u + 0x7FFF + ((c.u >> 16) & 1);   // round-to-nearest-even
  return (u16)(u >> 16);
}

// ============ K1: partition (key,val) pairs into 196 row-range buckets ============
__global__ __launch_bounds__(256) void partition_kernel(const int* __restrict__ nidx,
                                                        const int* __restrict__ eidx,
                                                        int* __restrict__ gcnt,
                                                        uint2* __restrict__ bk) {
  const int dir = blockIdx.y;                      // 0: key=eidx, 1: key=nidx
  const int* __restrict__ key = dir ? nidx : eidx;
  const int* __restrict__ val = dir ? eidx : nidx;
  int* __restrict__ cnt = gcnt + dir * NBK;
  uint2* __restrict__ bkd = bk + (size_t)dir * NBK * BKCAP;
  __shared__ int lcnt[NBK], lbase[NBK];
  const int tid = threadIdx.x;
  const int j0 = blockIdx.x * TILE;
  for (int i = tid; i < NBK; i += 256) lcnt[i] = 0;
  __syncthreads();
  int keys[16], vals[16];
  #pragma unroll
  for (int i = 0; i < 16; i++) {
    int j = j0 + tid + i * 256;
    if (j < NNZV) {
      keys[i] = __builtin_nontemporal_load(key + j);
      vals[i] = __builtin_nontemporal_load(val + j);
      atomicAdd(&lcnt[keys[i] >> 9], 1);
    } else keys[i] = -1;
  }
  __syncthreads();
  for (int b = tid; b < NBK; b += 256) {
    int c = lcnt[b];
    lbase[b] = c ? atomicAdd(&cnt[b], c) : 0;
    lcnt[b] = 0;
  }
  __syncthreads();
  #pragma unroll
  for (int i = 0; i < 16; i++) {
    if (keys[i] >= 0) {
      int b = keys[i] >> 9;
      int p = lbase[b] + atomicAdd(&lcnt[b], 1);
      if (p < BKCAP)
        bkd[(size_t)b * BKCAP + p] = make_uint2((unsigned)keys[i], (unsigned)vals[i]);
    }
  }
}

// ===== K2: per-bucket counting sort -> off[] + col[]; scatter stays in hot L2 =====
__global__ __launch_bounds__(512) void bucket_sort_kernel(const int* __restrict__ gcnt,
                                                          const uint2* __restrict__ bk,
                                                          int* __restrict__ off_e, int* __restrict__ off_v,
                                                          int* __restrict__ col_e, int* __restrict__ col_v) {
  const int gb = blockIdx.x;                       // 0..2*NBK-1
  const int dir = gb >= NBK ? 1 : 0;
  const int b = dir ? gb - NBK : gb;
  const int* __restrict__ cnt = gcnt + dir * NBK;
  const uint2* __restrict__ bkd = bk + ((size_t)dir * NBK + b) * BKCAP;
  int* __restrict__ off = dir ? off_v : off_e;
  int* __restrict__ col = dir ? col_v : col_e;
  const int tid = threadIdx.x, lane = tid & 63, wid = tid >> 6;
  __shared__ int lcnt[512];
  __shared__ int wsum[8];
  __shared__ int base_s;
  if (tid < 64) {                                   // base = sum cnt[0..b)
    int s = 0;
    for (int t = tid; t < b; t += 64) s += cnt[t];
    #pragma unroll
    for (int d = 1; d < 64; d <<= 1) s += __shfl_xor(s, d);
    if (tid == 0) base_s = s;
  }
  lcnt[tid] = 0;
  __syncthreads();
  const int n = min(cnt[b], BKCAP);
  const int r0 = b << 9;
  for (int i = tid; i < n; i += 512)
    atomicAdd(&lcnt[bkd[i].x - r0], 1);
  __syncthreads();
  int x = lcnt[tid];                                // per-row count
  int inc = x;
  #pragma unroll
  for (int d = 1; d < 64; d <<= 1) { int t = __shfl_up(inc, d); if (lane >= d) inc += t; }
  if (lane == 63) wsum[wid] = inc;
  __syncthreads();
  int wbase = 0;
  for (int k = 0; k < wid; k++) wbase += wsum[k];
  const int gpos = base_s + wbase + inc - x;        // global exclusive position for row tid
  const int row = r0 + tid;
  if (row < NODES) off[row] = gpos;
  if (b == NBK - 1 && tid == 0) off[NODES] = NNZV;
  __syncthreads();
  lcnt[tid] = gpos;                                 // cursor = global position
  __syncthreads();
  for (int i = tid; i < n; i += 512) {
    uint2 e = bkd[i];
    int p = atomicAdd(&lcnt[e.x - r0], 1);
    col[p] = (int)e.y;
  }
}

// ======= GEMM: Y[M,N](bf16) = X[M,128] @ W[128,N];  X is f32 (XBF=0) or bf16 (XBF=1) =======
template<int N, bool XBF>
__global__ __launch_bounds__(256) void gemm_kernel(const void* __restrict__ Xv,
                                                   const float* __restrict__ W,
                                                   u16* __restrict__ Y, int M) {
  __shared__ float sW[128 * N];
  __shared__ float sX[4][8 * 128];
  const int tid = threadIdx.x, wave = tid >> 6, lane = tid & 63;
  for (int i = tid * 4; i < 128 * N; i += 1024)
    *(float4*)(sW + i) = *(const float4*)(W + i);
  __syncthreads();
  constexpr int CPL = N / 64;
  for (int chunk = blockIdx.x * 32; chunk < M; chunk += gridDim.x * 32) {
    const int row0 = chunk + wave * 8;
    if constexpr (XBF) {
      const u16* src = (const u16*)Xv + (size_t)row0 * 128;
      #pragma unroll
      for (int it = 0; it < 4; it++) {
        ushort4 v = *(const ushort4*)(src + (size_t)(lane + 64 * it) * 4);
        ((float4*)sX[wave])[lane + 64 * it] = make_float4(b2f(v.x), b2f(v.y), b2f(v.z), b2f(v.w));
      }
    } else {
      const float4* src = (const float4*)((const float*)Xv + (size_t)row0 * 128);
      #pragma unroll
      for (int i = 0; i < 4; i++) ((float4*)sX[wave])[lane + 64 * i] = src[lane + 64 * i];
    }
    float acc[8][CPL];
    #pragma unroll
    for (int r = 0; r < 8; r++)
      #pragma unroll
      for (int c = 0; c < CPL; c++) acc[r][c] = 0.f;
    const float* xw = sX[wave];
    #pragma unroll 2
    for (int k = 0; k < 128; k += 4) {
      float4 xr[8];
      #pragma unroll
      for (int r = 0; r < 8; r++) xr[r] = *(const float4*)(xw + r * 128 + k);
      #pragma unroll
      for (int kk = 0; kk < 4; kk++) {
        #pragma unroll
        for (int c = 0; c < CPL; c++) {
          float w = sW[(k + kk) * N + lane + 64 * c];
          #pragma unroll
          for (int r = 0; r < 8; r++)
            acc[r][c] = fmaf(((const float*)&xr[r])[kk], w, acc[r][c]);
        }
      }
    }
    #pragma unroll
    for (int r = 0; r < 8; r++)
      #pragma unroll
      for (int c = 0; c < CPL; c++)
        Y[(size_t)(row0 + r) * N + lane + 64 * c] = f2b(acc[r][c]);
  }
}

// ========== gather node->edge (bf16->bf16): dst[e] = (1/deg_e) * sum src[v] ==========
template<int F>
__global__ __launch_bounds__(256) void gather_n2e(const int* __restrict__ off, const int* __restrict__ col,
                                                  const u16* __restrict__ src, u16* __restrict__ dst,
                                                  int nrows) {
  const int row = blockIdx.x * 4 + (threadIdx.x >> 6);
  if (row >= nrows) return;
  const int lane = threadIdx.x & 63;
  const int s0 = off[row], s1 = off[row + 1];
  float a0 = 0.f, a1 = 0.f, b0 = 0.f, b1 = 0.f, c0a = 0.f, c1a = 0.f, d0 = 0.f, d1 = 0.f;
  int k = s0;
  for (; k + 3 < s1; k += 4) {
    int i0 = col[k], i1 = col[k + 1], i2 = col[k + 2], i3 = col[k + 3];
    if constexpr (F == 128) {
      ushort2 u0 = *(const ushort2*)(src + (size_t)i0 * F + lane * 2);
      ushort2 u1 = *(const ushort2*)(src + (size_t)i1 * F + lane * 2);
      ushort2 u2 = *(const ushort2*)(src + (size_t)i2 * F + lane * 2);
      ushort2 u3 = *(const ushort2*)(src + (size_t)i3 * F + lane * 2);
      a0 += b2f(u0.x); a1 += b2f(u0.y); b0 += b2f(u1.x); b1 += b2f(u1.y);
      c0a += b2f(u2.x); c1a += b2f(u2.y); d0 += b2f(u3.x); d1 += b2f(u3.y);
    } else {
      a0 += b2f(src[(size_t)i0 * F + lane]); b0 += b2f(src[(size_t)i1 * F + lane]);
      c0a += b2f(src[(size_t)i2 * F + lane]); d0 += b2f(src[(size_t)i3 * F + lane]);
    }
  }
  for (; k < s1; k++) {
    int i0 = col[k];
    if constexpr (F == 128) {
      ushort2 u0 = *(const ushort2*)(src + (size_t)i0 * F + lane * 2);
      a0 += b2f(u0.x); a1 += b2f(u0.y);
    } else a0 += b2f(src[(size_t)i0 * F + lane]);
  }
  const float sc = (s1 > s0) ? 1.0f / (float)(s1 - s0) : 0.f;
  if constexpr (F == 128) {
    ushort2 o; o.x = f2b((a0 + b0 + c0a + d0) * sc); o.y = f2b((a1 + b1 + c1a + d1) * sc);
    *(ushort2*)(dst + (size_t)row * F + lane * 2) = o;
  } else {
    dst[(size_t)row * F + lane] = f2b((a0 + b0 + c0a + d0) * sc);
  }
}

// == gather edge->node + bias (+relu): out[v] = [relu]((1/deg_v)*sum src[e] + b); dst bf16 or f32 ==
template<int F, bool RELU, bool DSTBF>
__global__ __launch_bounds__(256) void gather_e2n(const int* __restrict__ off, const int* __restrict__ col,
                                                  const u16* __restrict__ src, const float* __restrict__ bias,
                                                  void* __restrict__ dstv, int nrows) {
  const int row = blockIdx.x * 4 + (threadIdx.x >> 6);
  if (row >= nrows) return;
  const int lane = threadIdx.x & 63;
  const int s0 = off[row], s1 = off[row + 1];
  float a0 = 0.f, a1 = 0.f, b0 = 0.f, b1 = 0.f, c0a = 0.f, c1a = 0.f, d0 = 0.f, d1 = 0.f;
  int k = s0;
  for (; k + 3 < s1; k += 4) {
    int i0 = col[k], i1 = col[k + 1], i2 = col[k + 2], i3 = col[k + 3];
    if constexpr (F == 128) {
      ushort2 u0 = *(const ushort2*)(src + (size_t)i0 * F + lane * 2);
      ushort2 u1 = *(const ushort2*)(src + (size_t)i1 * F + lane * 2);
      ushort2 u2 = *(const ushort2*)(src + (size_t)i2 * F + lane * 2);
      ushort2 u3 = *(const ushort2*)(src + (size_t)i3 * F + lane * 2);
      a0 += b2f(u0.x); a1 += b2f(u0.y); b0 += b2f(u1.x); b1 += b2f(u1.y);
      c0a += b2f(u2.x); c1a += b2f(u2.y); d0 += b2f(u3.x); d1 += b2f(u3.y);
    } else {
      a0 += b2f(src[(size_t)i0 * F + lane]); b0 += b2f(src[(size_t)i1 * F + lane]);
      c0a += b2f(src[(size_t)i2 * F + lane]); d0 += b2f(src[(size_t)i3 * F + lane]);
    }
  }
  for (; k < s1; k++) {
    int i0 = col[k];
    if constexpr (F == 128) {
      ushort2 u0 = *(const ushort2*)(src + (size_t)i0 * F + lane * 2);
      a0 += b2f(u0.x); a1 += b2f(u0.y);
    } else a0 += b2f(src[(size_t)i0 * F + lane]);
  }
  const float sc = (s1 > s0) ? 1.0f / (float)(s1 - s0) : 0.f;
  if constexpr (F == 128) {
    float v0 = (a0 + b0 + c0a + d0) * sc + bias[lane * 2];
    float v1 = (a1 + b1 + c1a + d1) * sc + bias[lane * 2 + 1];
    if (RELU) { v0 = fmaxf(v0, 0.f); v1 = fmaxf(v1, 0.f); }
    if constexpr (DSTBF) {
      ushort2 o; o.x = f2b(v0); o.y = f2b(v1);
      *(ushort2*)((u16*)dstv + (size_t)row * F + lane * 2) = o;
    } else {
      *(float2*)((float*)dstv + (size_t)row * F + lane * 2) = make_float2(v0, v1);
    }
  } else {
    float v0 = (a0 + b0 + c0a + d0) * sc + bias[lane];
    if (RELU) v0 = fmaxf(v0, 0.f);
    if constexpr (DSTBF) ((u16*)dstv)[(size_t)row * F + lane] = f2b(v0);
    else ((float*)dstv)[(size_t)row * F + lane] = v0;
  }
}

extern "C" void kernel_launch(void* const* d_in, const int* in_sizes, int n_in,
                              void* d_out, int out_size, void* d_ws, size_t ws_size,
                              hipStream_t stream) {
  const float* x  = (const float*)d_in[0];
  const int*   hi = (const int*)d_in[1];
  const float* W1 = (const float*)d_in[2];
  const float* b1 = (const float*)d_in[3];
  const float* W2 = (const float*)d_in[4];
  const float* b2 = (const float*)d_in[5];
  float* out = (float*)d_out;
  const int* nidx = hi;             // row 0: node indices
  const int* eidx = hi + NNZV;      // row 1: edge indices

  char* w = (char*)d_ws;
  int*   off_e = (int*)w;                           // 100001 ints
  int*   off_v = (int*)(w + 524288);                // 100001 ints
  int*   gcnt  = (int*)(w + 1048576);               // 392 ints (bucket counts)
  int*   col_e = (int*)(w + 2097152);               // 1.6M ints
  int*   col_v = (int*)(w + 8650752);               // 1.6M ints
  uint2* bk    = (uint2*)(w + 16777216);            // 2*196*12288*8B = 38.5 MB
  u16*   bufH  = (u16*)(w + 56623104);              // 25.6 MB: h1, then h2, then m2e
  u16*   bufM  = (u16*)(w + 56623104 + 25600000);   // 25.6 MB: m_e, then g2

  // ---- CSR build: partition -> per-bucket counting sort ----
  hipMemsetAsync(gcnt, 0, 392 * 4, stream);
  partition_kernel<<<dim3(NTIL, 2), 256, 0, stream>>>(nidx, eidx, gcnt, bk);
  bucket_sort_kernel<<<2 * NBK, 512, 0, stream>>>(gcnt, bk, off_e, off_v, col_e, col_v);

  // ---- conv1 (F=128) ----
  gemm_kernel<128, false><<<512, 256, 0, stream>>>(x, W1, bufH, NODES);            // h1(bf16)
  gather_n2e<128><<<(EDGES + 3) / 4, 256, 0, stream>>>(off_e, col_e, bufH, bufM, EDGES);   // m_e
  gather_e2n<128, true, true><<<(NODES + 3) / 4, 256, 0, stream>>>(off_v, col_v, bufM, b1, bufH, NODES); // h2

  // ---- conv2 (F=64) ----
  gemm_kernel<64, true><<<512, 256, 0, stream>>>(bufH, W2, bufM, NODES);           // g2(bf16)
  gather_n2e<64><<<(EDGES + 3) / 4, 256, 0, stream>>>(off_e, col_e, bufM, bufH, EDGES);    // m2e
  gather_e2n<64, false, false><<<(NODES + 3) / 4, 256, 0, stream>>>(off_v, col_v, bufH, b2, out, NODES);
}

// Round 6
// 367.793 us; speedup vs baseline: 2.2809x; 1.2645x over previous
//
#include <hip/hip_runtime.h>

#define NODES 100000
#define EDGES 100000
#define NNZV  1600000
#define NBK   196          // buckets per direction (512 rows each)
#define BKCAP 12288        // entry capacity per bucket (mean 8192)
#define TILE  4096         // entries per partition block (256 thr x 16)
#define NTIL  391          // ceil(NNZV / TILE)

typedef unsigned short u16;
typedef __attribute__((ext_vector_type(8))) short bf16x8;   // 8 bf16 (4 VGPRs)
typedef __attribute__((ext_vector_type(4))) float f32x4;

__device__ __forceinline__ float b2f(u16 h) {
  union { unsigned u; float f; } c; c.u = ((unsigned)h) << 16; return c.f;
}
__device__ __forceinline__ u16 f2b(float f) {
  union { unsigned u; float f; } c; c.f = f;
  unsigned u = c.u + 0x7FFF + ((c.u >> 16) & 1);   // round-to-nearest-even
  return (u16)(u >> 16);
}

// ============ W pre-transpose: W1T[n][128] = bf16(W1[k][n]), same for W2 ============
__global__ __launch_bounds__(256) void wtrans_kernel(const float* __restrict__ W1,
                                                     const float* __restrict__ W2,
                                                     u16* __restrict__ W1T, u16* __restrict__ W2T) {
  int i = blockIdx.x * 256 + threadIdx.x;
  if (i < 16384) {
    int k = i >> 7, n = i & 127;
    W1T[n * 128 + k] = f2b(W1[i]);
  } else if (i < 16384 + 8192) {
    int j = i - 16384;
    int k = j >> 6, n = j & 63;
    W2T[n * 128 + k] = f2b(W2[j]);
  }
}

// ============ K1: partition packed (local9|val17) entries into 196 buckets ============
__global__ __launch_bounds__(256) void partition_kernel(const int* __restrict__ nidx,
                                                        const int* __restrict__ eidx,
                                                        int* __restrict__ gcnt,
                                                        unsigned* __restrict__ bk) {
  const int dir = blockIdx.y;                      // 0: key=eidx, 1: key=nidx
  const int* __restrict__ key = dir ? nidx : eidx;
  const int* __restrict__ val = dir ? eidx : nidx;
  int* __restrict__ cnt = gcnt + dir * NBK;
  unsigned* __restrict__ bkd = bk + (size_t)dir * NBK * BKCAP;
  __shared__ int lcnt[NBK], lbase[NBK];
  const int tid = threadIdx.x;
  const int j0 = blockIdx.x * TILE;
  for (int i = tid; i < NBK; i += 256) lcnt[i] = 0;
  __syncthreads();
  int bidx[16]; unsigned pk[16];
  #pragma unroll
  for (int i = 0; i < 16; i++) {
    int j = j0 + tid + i * 256;
    if (j < NNZV) {
      int k = __builtin_nontemporal_load(key + j);
      int v = __builtin_nontemporal_load(val + j);
      bidx[i] = k >> 9;
      pk[i] = ((unsigned)(k & 511) << 17) | (unsigned)v;
      atomicAdd(&lcnt[bidx[i]], 1);
    } else bidx[i] = -1;
  }
  __syncthreads();
  for (int b = tid; b < NBK; b += 256) {
    int c = lcnt[b];
    lbase[b] = c ? atomicAdd(&cnt[b], c) : 0;
    lcnt[b] = 0;
  }
  __syncthreads();
  #pragma unroll
  for (int i = 0; i < 16; i++) {
    if (bidx[i] >= 0) {
      int p = lbase[bidx[i]] + atomicAdd(&lcnt[bidx[i]], 1);
      if (p < BKCAP)
        bkd[(size_t)bidx[i] * BKCAP + p] = pk[i];
    }
  }
}

// ===== K2: per-bucket counting sort -> off[] + col[]; scatter stays in hot L2 =====
__global__ __launch_bounds__(512) void bucket_sort_kernel(const int* __restrict__ gcnt,
                                                          const unsigned* __restrict__ bk,
                                                          int* __restrict__ off_e, int* __restrict__ off_v,
                                                          int* __restrict__ col_e, int* __restrict__ col_v) {
  const int gb = blockIdx.x;                       // 0..2*NBK-1
  const int dir = gb >= NBK ? 1 : 0;
  const int b = dir ? gb - NBK : gb;
  const int* __restrict__ cnt = gcnt + dir * NBK;
  const unsigned* __restrict__ bkd = bk + ((size_t)dir * NBK + b) * BKCAP;
  int* __restrict__ off = dir ? off_v : off_e;
  int* __restrict__ col = dir ? col_v : col_e;
  const int tid = threadIdx.x, lane = tid & 63, wid = tid >> 6;
  __shared__ int lcnt[512];
  __shared__ int wsum[8];
  __shared__ int base_s;
  if (tid < 64) {                                   // base = sum cnt[0..b)
    int s = 0;
    for (int t = tid; t < b; t += 64) s += cnt[t];
    #pragma unroll
    for (int d = 1; d < 64; d <<= 1) s += __shfl_xor(s, d);
    if (tid == 0) base_s = s;
  }
  lcnt[tid] = 0;
  __syncthreads();
  const int n = min(cnt[b], BKCAP);
  for (int i = tid; i < n; i += 512)
    atomicAdd(&lcnt[bkd[i] >> 17], 1);
  __syncthreads();
  int x = lcnt[tid];                                // per-row count
  int inc = x;
  #pragma unroll
  for (int d = 1; d < 64; d <<= 1) { int t = __shfl_up(inc, d); if (lane >= d) inc += t; }
  if (lane == 63) wsum[wid] = inc;
  __syncthreads();
  int wbase = 0;
  for (int k = 0; k < wid; k++) wbase += wsum[k];
  const int gpos = base_s + wbase + inc - x;        // global exclusive position for row tid
  const int row = (b << 9) + tid;
  if (row < NODES) off[row] = gpos;
  if (b == NBK - 1 && tid == 0) off[NODES] = NNZV;
  __syncthreads();
  lcnt[tid] = gpos;                                 // cursor = global position
  __syncthreads();
  for (int i = tid; i < n; i += 512) {
    unsigned e = bkd[i];
    int p = atomicAdd(&lcnt[e >> 17], 1);
    col[p] = (int)(e & 0x1FFFFu);
  }
}

// ======= MFMA GEMM: Y[M,N](bf16) = X[M,128] @ W[128,N]; WT is pre-transposed bf16 [N][128] =======
// Block: 256 thr = 4 waves (2x2), tile M=64 x N. LDS rows padded to 136 bf16 (2-way banks only).
template<int N, bool XBF>
__global__ __launch_bounds__(256) void gemm_kernel(const void* __restrict__ Xv,
                                                   const u16* __restrict__ WT,
                                                   u16* __restrict__ Y, int M) {
  __shared__ u16 sX[64 * 136];
  __shared__ u16 sW[N * 136];
  const int tid = threadIdx.x, lane = tid & 63, w = tid >> 6;
  const int chunk = blockIdx.x * 64;
  // stage W (linear ushort8 -> b128 writes)
  constexpr int WV = N * 128 / 8;
  for (int t = tid; t < WV; t += 256) {
    int e = t * 8, n = e >> 7, k = e & 127;
    *(bf16x8*)(sW + n * 136 + k) = *(const bf16x8*)(WT + n * 128 + k);
  }
  // stage X
  if constexpr (XBF) {
    const u16* X = (const u16*)Xv;
    for (int t = tid; t < 1024; t += 256) {          // 64*128/8
      int e = t * 8, r = e >> 7, k = e & 127;
      int row = min(chunk + r, M - 1);
      *(bf16x8*)(sX + r * 136 + k) = *(const bf16x8*)(X + (size_t)row * 128 + k);
    }
  } else {
    const float* X = (const float*)Xv;
    for (int t = tid; t < 2048; t += 256) {          // 64 rows x 32 float4
      int r = t >> 5, c4 = t & 31;
      int row = min(chunk + r, M - 1);
      float4 v = *(const float4*)(X + (size_t)row * 128 + c4 * 4);
      ushort4 o = { f2b(v.x), f2b(v.y), f2b(v.z), f2b(v.w) };
      *(ushort4*)(sX + r * 136 + c4 * 4) = o;
    }
  }
  __syncthreads();
  constexpr int CW = N / 2;            // cols per wave
  constexpr int NT = CW / 16;          // col tiles per wave
  const int wr = w >> 1, wc = w & 1;
  const int l15 = lane & 15;
  const int arow = wr * 32 + l15;
  const int kb = (lane >> 4) * 8;
  f32x4 acc[2][NT];
  #pragma unroll
  for (int rt = 0; rt < 2; rt++)
    #pragma unroll
    for (int nt = 0; nt < NT; nt++) acc[rt][nt] = (f32x4){0.f, 0.f, 0.f, 0.f};
  #pragma unroll
  for (int kk = 0; kk < 4; kk++) {
    const int ko = kk * 32 + kb;
    bf16x8 a0 = *(const bf16x8*)(sX + arow * 136 + ko);
    bf16x8 a1 = *(const bf16x8*)(sX + (arow + 16) * 136 + ko);
    #pragma unroll
    for (int nt = 0; nt < NT; nt++) {
      bf16x8 bb = *(const bf16x8*)(sW + (wc * CW + nt * 16 + l15) * 136 + ko);
      acc[0][nt] = __builtin_amdgcn_mfma_f32_16x16x32_bf16(a0, bb, acc[0][nt], 0, 0, 0);
      acc[1][nt] = __builtin_amdgcn_mfma_f32_16x16x32_bf16(a1, bb, acc[1][nt], 0, 0, 0);
    }
  }
  // C/D layout (m89-verified): col = lane&15, row = (lane>>4)*4 + r
  const int r4 = (lane >> 4) * 4;
  #pragma unroll
  for (int rt = 0; rt < 2; rt++)
    #pragma unroll
    for (int r = 0; r < 4; r++) {
      int row = chunk + wr * 32 + rt * 16 + r4 + r;
      if (row < M) {
        #pragma unroll
        for (int nt = 0; nt < NT; nt++)
          Y[(size_t)row * N + wc * CW + nt * 16 + l15] = f2b(acc[rt][nt][r]);
      }
    }
}

// ========== gather node->edge (bf16->bf16): dst[e] = (1/deg_e) * sum src[v] ==========
template<int F>
__global__ __launch_bounds__(256) void gather_n2e(const int* __restrict__ off, const int* __restrict__ col,
                                                  const u16* __restrict__ src, u16* __restrict__ dst,
                                                  int nrows) {
  const int row = blockIdx.x * 4 + (threadIdx.x >> 6);
  if (row >= nrows) return;
  const int lane = threadIdx.x & 63;
  const int s0 = off[row], s1 = off[row + 1];
  float a0 = 0.f, a1 = 0.f, b0 = 0.f, b1 = 0.f, c0 = 0.f, c1 = 0.f, d0 = 0.f, d1 = 0.f;
  int k = s0;
  for (; k + 7 < s1; k += 8) {                      // 8 outstanding row loads
    int i0 = col[k], i1 = col[k + 1], i2 = col[k + 2], i3 = col[k + 3];
    int i4 = col[k + 4], i5 = col[k + 5], i6 = col[k + 6], i7 = col[k + 7];
    if constexpr (F == 128) {
      ushort2 u0 = *(const ushort2*)(src + (size_t)i0 * F + lane * 2);
      ushort2 u1 = *(const ushort2*)(src + (size_t)i1 * F + lane * 2);
      ushort2 u2 = *(const ushort2*)(src + (size_t)i2 * F + lane * 2);
      ushort2 u3 = *(const ushort2*)(src + (size_t)i3 * F + lane * 2);
      ushort2 u4 = *(const ushort2*)(src + (size_t)i4 * F + lane * 2);
      ushort2 u5 = *(const ushort2*)(src + (size_t)i5 * F + lane * 2);
      ushort2 u6 = *(const ushort2*)(src + (size_t)i6 * F + lane * 2);
      ushort2 u7 = *(const ushort2*)(src + (size_t)i7 * F + lane * 2);
      a0 += b2f(u0.x); a1 += b2f(u0.y); b0 += b2f(u1.x); b1 += b2f(u1.y);
      c0 += b2f(u2.x); c1 += b2f(u2.y); d0 += b2f(u3.x); d1 += b2f(u3.y);
      a0 += b2f(u4.x); a1 += b2f(u4.y); b0 += b2f(u5.x); b1 += b2f(u5.y);
      c0 += b2f(u6.x); c1 += b2f(u6.y); d0 += b2f(u7.x); d1 += b2f(u7.y);
    } else {
      u16 u0 = src[(size_t)i0 * F + lane], u1 = src[(size_t)i1 * F + lane];
      u16 u2 = src[(size_t)i2 * F + lane], u3 = src[(size_t)i3 * F + lane];
      u16 u4 = src[(size_t)i4 * F + lane], u5 = src[(size_t)i5 * F + lane];
      u16 u6 = src[(size_t)i6 * F + lane], u7 = src[(size_t)i7 * F + lane];
      a0 += b2f(u0); b0 += b2f(u1); c0 += b2f(u2); d0 += b2f(u3);
      a0 += b2f(u4); b0 += b2f(u5); c0 += b2f(u6); d0 += b2f(u7);
    }
  }
  for (; k < s1; k++) {
    int i0 = col[k];
    if constexpr (F == 128) {
      ushort2 u0 = *(const ushort2*)(src + (size_t)i0 * F + lane * 2);
      a0 += b2f(u0.x); a1 += b2f(u0.y);
    } else a0 += b2f(src[(size_t)i0 * F + lane]);
  }
  const float sc = (s1 > s0) ? 1.0f / (float)(s1 - s0) : 0.f;
  if constexpr (F == 128) {
    ushort2 o; o.x = f2b((a0 + b0 + c0 + d0) * sc); o.y = f2b((a1 + b1 + c1 + d1) * sc);
    *(ushort2*)(dst + (size_t)row * F + lane * 2) = o;
  } else {
    dst[(size_t)row * F + lane] = f2b((a0 + b0 + c0 + d0) * sc);
  }
}

// == gather edge->node + bias (+relu): out[v] = [relu]((1/deg_v)*sum src[e] + b); dst bf16 or f32 ==
template<int F, bool RELU, bool DSTBF>
__global__ __launch_bounds__(256) void gather_e2n(const int* __restrict__ off, const int* __restrict__ col,
                                                  const u16* __restrict__ src, const float* __restrict__ bias,
                                                  void* __restrict__ dstv, int nrows) {
  const int row = blockIdx.x * 4 + (threadIdx.x >> 6);
  if (row >= nrows) return;
  const int lane = threadIdx.x & 63;
  const int s0 = off[row], s1 = off[row + 1];
  float a0 = 0.f, a1 = 0.f, b0 = 0.f, b1 = 0.f, c0 = 0.f, c1 = 0.f, d0 = 0.f, d1 = 0.f;
  int k = s0;
  for (; k + 7 < s1; k += 8) {
    int i0 = col[k], i1 = col[k + 1], i2 = col[k + 2], i3 = col[k + 3];
    int i4 = col[k + 4], i5 = col[k + 5], i6 = col[k + 6], i7 = col[k + 7];
    if constexpr (F == 128) {
      ushort2 u0 = *(const ushort2*)(src + (size_t)i0 * F + lane * 2);
      ushort2 u1 = *(const ushort2*)(src + (size_t)i1 * F + lane * 2);
      ushort2 u2 = *(const ushort2*)(src + (size_t)i2 * F + lane * 2);
      ushort2 u3 = *(const ushort2*)(src + (size_t)i3 * F + lane * 2);
      ushort2 u4 = *(const ushort2*)(src + (size_t)i4 * F + lane * 2);
      ushort2 u5 = *(const ushort2*)(src + (size_t)i5 * F + lane * 2);
      ushort2 u6 = *(const ushort2*)(src + (size_t)i6 * F + lane * 2);
      ushort2 u7 = *(const ushort2*)(src + (size_t)i7 * F + lane * 2);
      a0 += b2f(u0.x); a1 += b2f(u0.y); b0 += b2f(u1.x); b1 += b2f(u1.y);
      c0 += b2f(u2.x); c1 += b2f(u2.y); d0 += b2f(u3.x); d1 += b2f(u3.y);
      a0 += b2f(u4.x); a1 += b2f(u4.y); b0 += b2f(u5.x); b1 += b2f(u5.y);
      c0 += b2f(u6.x); c1 += b2f(u6.y); d0 += b2f(u7.x); d1 += b2f(u7.y);
    } else {
      u16 u0 = src[(size_t)i0 * F + lane], u1 = src[(size_t)i1 * F + lane];
      u16 u2 = src[(size_t)i2 * F + lane], u3 = src[(size_t)i3 * F + lane];
      u16 u4 = src[(size_t)i4 * F + lane], u5 = src[(size_t)i5 * F + lane];
      u16 u6 = src[(size_t)i6 * F + lane], u7 = src[(size_t)i7 * F + lane];
      a0 += b2f(u0); b0 += b2f(u1); c0 += b2f(u2); d0 += b2f(u3);
      a0 += b2f(u4); b0 += b2f(u5); c0 += b2f(u6); d0 += b2f(u7);
    }
  }
  for (; k < s1; k++) {
    int i0 = col[k];
    if constexpr (F == 128) {
      ushort2 u0 = *(const ushort2*)(src + (size_t)i0 * F + lane * 2);
      a0 += b2f(u0.x); a1 += b2f(u0.y);
    } else a0 += b2f(src[(size_t)i0 * F + lane]);
  }
  const float sc = (s1 > s0) ? 1.0f / (float)(s1 - s0) : 0.f;
  if constexpr (F == 128) {
    float v0 = (a0 + b0 + c0 + d0) * sc + bias[lane * 2];
    float v1 = (a1 + b1 + c1 + d1) * sc + bias[lane * 2 + 1];
    if (RELU) { v0 = fmaxf(v0, 0.f); v1 = fmaxf(v1, 0.f); }
    if constexpr (DSTBF) {
      ushort2 o; o.x = f2b(v0); o.y = f2b(v1);
      *(ushort2*)((u16*)dstv + (size_t)row * F + lane * 2) = o;
    } else {
      *(float2*)((float*)dstv + (size_t)row * F + lane * 2) = make_float2(v0, v1);
    }
  } else {
    float v0 = (a0 + b0 + c0 + d0) * sc + bias[lane];
    if (RELU) v0 = fmaxf(v0, 0.f);
    if constexpr (DSTBF) ((u16*)dstv)[(size_t)row * F + lane] = f2b(v0);
    else ((float*)dstv)[(size_t)row * F + lane] = v0;
  }
}

extern "C" void kernel_launch(void* const* d_in, const int* in_sizes, int n_in,
                              void* d_out, int out_size, void* d_ws, size_t ws_size,
                              hipStream_t stream) {
  const float* x  = (const float*)d_in[0];
  const int*   hi = (const int*)d_in[1];
  const float* W1 = (const float*)d_in[2];
  const float* b1 = (const float*)d_in[3];
  const float* W2 = (const float*)d_in[4];
  const float* b2 = (const float*)d_in[5];
  float* out = (float*)d_out;
  const int* nidx = hi;             // row 0: node indices
  const int* eidx = hi + NNZV;      // row 1: edge indices

  char* w = (char*)d_ws;
  int*      off_e = (int*)w;                           // 100001 ints
  int*      off_v = (int*)(w + 524288);                // 100001 ints
  int*      gcnt  = (int*)(w + 1048576);               // 392 ints
  u16*      W1T   = (u16*)(w + 1052672);               // 128x128 bf16 (32 KB)
  u16*      W2T   = (u16*)(w + 1085440);               // 64x128 bf16 (16 KB)
  int*      col_e = (int*)(w + 2097152);               // 1.6M ints
  int*      col_v = (int*)(w + 8650752);               // 1.6M ints
  unsigned* bk    = (unsigned*)(w + 16777216);         // 2*196*12288*4B = 19.3 MB
  u16*      bufH  = (u16*)(w + 56623104);              // 25.6 MB: h1, then h2, then m2e
  u16*      bufM  = (u16*)(w + 56623104 + 25600000);   // 25.6 MB: m_e, then g2

  // ---- weight pre-transpose + CSR build ----
  hipMemsetAsync(gcnt, 0, 392 * 4, stream);
  wtrans_kernel<<<96, 256, 0, stream>>>(W1, W2, W1T, W2T);
  partition_kernel<<<dim3(NTIL, 2), 256, 0, stream>>>(nidx, eidx, gcnt, bk);
  bucket_sort_kernel<<<2 * NBK, 512, 0, stream>>>(gcnt, bk, off_e, off_v, col_e, col_v);

  // ---- conv1 (F=128) ----
  gemm_kernel<128, false><<<1563, 256, 0, stream>>>(x, W1T, bufH, NODES);          // h1(bf16)
  gather_n2e<128><<<(EDGES + 3) / 4, 256, 0, stream>>>(off_e, col_e, bufH, bufM, EDGES);   // m_e
  gather_e2n<128, true, true><<<(NODES + 3) / 4, 256, 0, stream>>>(off_v, col_v, bufM, b1, bufH, NODES); // h2

  // ---- conv2 (F=64) ----
  gemm_kernel<64, true><<<1563, 256, 0, stream>>>(bufH, W2T, bufM, NODES);         // g2(bf16)
  gather_n2e<64><<<(EDGES + 3) / 4, 256, 0, stream>>>(off_e, col_e, bufM, bufH, EDGES);    // m2e
  gather_e2n<64, false, false><<<(NODES + 3) / 4, 256, 0, stream>>>(off_v, col_v, bufH, b2, out, NODES);
}

// Round 7
// 342.743 us; speedup vs baseline: 2.4476x; 1.0731x over previous
//
#include <hip/hip_runtime.h>

#define NODES 100000
#define EDGES 100000
#define NNZV  1600000
#define NBK   196          // buckets per direction (512 rows each)
#define BKCAP 12288        // entry capacity per bucket (mean 8192)
#define TILE2 2048         // entries per partition block (256 thr x 8, both dirs)
#define NTIL2 782          // ceil(NNZV / TILE2)

typedef unsigned short u16;
typedef __attribute__((ext_vector_type(8))) short bf16x8;   // 8 bf16 (4 VGPRs)
typedef __attribute__((ext_vector_type(4))) float f32x4;

__device__ __forceinline__ float b2f(u16 h) {
  union { unsigned u; float f; } c; c.u = ((unsigned)h) << 16; return c.f;
}
__device__ __forceinline__ u16 f2b(float f) {
  union { unsigned u; float f; } c; c.f = f;
  unsigned u = c.u + 0x7FFF + ((c.u >> 16) & 1);   // round-to-nearest-even
  return (u16)(u >> 16);
}

// ============ W pre-transpose: W1T[n][128] = bf16(W1[k][n]), same for W2 ============
__global__ __launch_bounds__(256) void wtrans_kernel(const float* __restrict__ W1,
                                                     const float* __restrict__ W2,
                                                     u16* __restrict__ W1T, u16* __restrict__ W2T) {
  int i = blockIdx.x * 256 + threadIdx.x;
  if (i < 16384) {
    int k = i >> 7, n = i & 127;
    W1T[n * 128 + k] = f2b(W1[i]);
  } else if (i < 16384 + 8192) {
    int j = i - 16384;
    int k = j >> 6, n = j & 63;
    W2T[n * 128 + k] = f2b(W2[j]);
  }
}

// ====== K1: single-pass dual-direction partition into 2x196 row-range buckets ======
__global__ __launch_bounds__(256) void partition_kernel(const int* __restrict__ nidx,
                                                        const int* __restrict__ eidx,
                                                        int* __restrict__ gcnt,
                                                        unsigned* __restrict__ bk) {
  __shared__ int lcnt_e[NBK], lcnt_n[NBK], lbase_e[NBK], lbase_n[NBK];
  const int tid = threadIdx.x;
  const int j0 = blockIdx.x * TILE2;
  for (int i = tid; i < NBK; i += 256) { lcnt_e[i] = 0; lcnt_n[i] = 0; }
  __syncthreads();
  int be[8], bn[8]; unsigned pe[8], pn[8];
  #pragma unroll
  for (int i = 0; i < 8; i++) {
    int j = j0 + tid + i * 256;
    if (j < NNZV) {
      int e = __builtin_nontemporal_load(eidx + j);
      int n = __builtin_nontemporal_load(nidx + j);
      be[i] = e >> 9; pe[i] = ((unsigned)(e & 511) << 17) | (unsigned)n;
      bn[i] = n >> 9; pn[i] = ((unsigned)(n & 511) << 17) | (unsigned)e;
      atomicAdd(&lcnt_e[be[i]], 1);
      atomicAdd(&lcnt_n[bn[i]], 1);
    } else { be[i] = -1; bn[i] = -1; }
  }
  __syncthreads();
  for (int b = tid; b < NBK; b += 256) {
    int c = lcnt_e[b];
    lbase_e[b] = c ? atomicAdd(&gcnt[b], c) : 0;
    lcnt_e[b] = 0;
    c = lcnt_n[b];
    lbase_n[b] = c ? atomicAdd(&gcnt[NBK + b], c) : 0;
    lcnt_n[b] = 0;
  }
  __syncthreads();
  #pragma unroll
  for (int i = 0; i < 8; i++) {
    if (be[i] >= 0) {
      int p = lbase_e[be[i]] + atomicAdd(&lcnt_e[be[i]], 1);
      if (p < BKCAP) bk[(size_t)be[i] * BKCAP + p] = pe[i];
      p = lbase_n[bn[i]] + atomicAdd(&lcnt_n[bn[i]], 1);
      if (p < BKCAP) bk[(size_t)(NBK + bn[i]) * BKCAP + p] = pn[i];
    }
  }
}

// ===== K2: per-bucket counting sort -> off[] + col[]; scatter stays in hot L2 =====
__global__ __launch_bounds__(512) void bucket_sort_kernel(const int* __restrict__ gcnt,
                                                          const unsigned* __restrict__ bk,
                                                          int* __restrict__ off_e, int* __restrict__ off_v,
                                                          int* __restrict__ col_e, int* __restrict__ col_v) {
  const int gb = blockIdx.x;                       // 0..2*NBK-1
  const int dir = gb >= NBK ? 1 : 0;
  const int b = dir ? gb - NBK : gb;
  const int* __restrict__ cnt = gcnt + dir * NBK;
  const unsigned* __restrict__ bkd = bk + ((size_t)dir * NBK + b) * BKCAP;
  int* __restrict__ off = dir ? off_v : off_e;
  int* __restrict__ col = dir ? col_v : col_e;
  const int tid = threadIdx.x, lane = tid & 63, wid = tid >> 6;
  __shared__ int lcnt[512];
  __shared__ int wsum[8];
  __shared__ int base_s;
  if (tid < 64) {                                   // base = sum cnt[0..b)
    int s = 0;
    for (int t = tid; t < b; t += 64) s += cnt[t];
    #pragma unroll
    for (int d = 1; d < 64; d <<= 1) s += __shfl_xor(s, d);
    if (tid == 0) base_s = s;
  }
  lcnt[tid] = 0;
  __syncthreads();
  const int n = min(cnt[b], BKCAP);
  for (int i = tid; i < n; i += 512)
    atomicAdd(&lcnt[bkd[i] >> 17], 1);
  __syncthreads();
  int x = lcnt[tid];                                // per-row count
  int inc = x;
  #pragma unroll
  for (int d = 1; d < 64; d <<= 1) { int t = __shfl_up(inc, d); if (lane >= d) inc += t; }
  if (lane == 63) wsum[wid] = inc;
  __syncthreads();
  int wbase = 0;
  for (int k = 0; k < wid; k++) wbase += wsum[k];
  const int gpos = base_s + wbase + inc - x;        // global exclusive position for row tid
  const int row = (b << 9) + tid;
  if (row < NODES) off[row] = gpos;
  if (b == NBK - 1 && tid == 0) off[NODES] = NNZV;
  __syncthreads();
  lcnt[tid] = gpos;                                 // cursor = global position
  __syncthreads();
  for (int i = tid; i < n; i += 512) {
    unsigned e = bkd[i];
    int p = atomicAdd(&lcnt[e >> 17], 1);
    col[p] = (int)(e & 0x1FFFFu);
  }
}

// ======= MFMA GEMM: Y[M,N](bf16) = X[M,128] @ W[128,N]; WT is pre-transposed bf16 [N][128] =======
template<int N, bool XBF>
__global__ __launch_bounds__(256) void gemm_kernel(const void* __restrict__ Xv,
                                                   const u16* __restrict__ WT,
                                                   u16* __restrict__ Y, int M) {
  __shared__ u16 sX[64 * 136];
  __shared__ u16 sW[N * 136];
  const int tid = threadIdx.x, lane = tid & 63, w = tid >> 6;
  const int chunk = blockIdx.x * 64;
  constexpr int WV = N * 128 / 8;
  for (int t = tid; t < WV; t += 256) {
    int e = t * 8, n = e >> 7, k = e & 127;
    *(bf16x8*)(sW + n * 136 + k) = *(const bf16x8*)(WT + n * 128 + k);
  }
  if constexpr (XBF) {
    const u16* X = (const u16*)Xv;
    for (int t = tid; t < 1024; t += 256) {
      int e = t * 8, r = e >> 7, k = e & 127;
      int row = min(chunk + r, M - 1);
      *(bf16x8*)(sX + r * 136 + k) = *(const bf16x8*)(X + (size_t)row * 128 + k);
    }
  } else {
    const float* X = (const float*)Xv;
    for (int t = tid; t < 2048; t += 256) {
      int r = t >> 5, c4 = t & 31;
      int row = min(chunk + r, M - 1);
      float4 v = *(const float4*)(X + (size_t)row * 128 + c4 * 4);
      ushort4 o = { f2b(v.x), f2b(v.y), f2b(v.z), f2b(v.w) };
      *(ushort4*)(sX + r * 136 + c4 * 4) = o;
    }
  }
  __syncthreads();
  constexpr int CW = N / 2;
  constexpr int NT = CW / 16;
  const int wr = w >> 1, wc = w & 1;
  const int l15 = lane & 15;
  const int arow = wr * 32 + l15;
  const int kb = (lane >> 4) * 8;
  f32x4 acc[2][NT];
  #pragma unroll
  for (int rt = 0; rt < 2; rt++)
    #pragma unroll
    for (int nt = 0; nt < NT; nt++) acc[rt][nt] = (f32x4){0.f, 0.f, 0.f, 0.f};
  #pragma unroll
  for (int kk = 0; kk < 4; kk++) {
    const int ko = kk * 32 + kb;
    bf16x8 a0 = *(const bf16x8*)(sX + arow * 136 + ko);
    bf16x8 a1 = *(const bf16x8*)(sX + (arow + 16) * 136 + ko);
    #pragma unroll
    for (int nt = 0; nt < NT; nt++) {
      bf16x8 bb = *(const bf16x8*)(sW + (wc * CW + nt * 16 + l15) * 136 + ko);
      acc[0][nt] = __builtin_amdgcn_mfma_f32_16x16x32_bf16(a0, bb, acc[0][nt], 0, 0, 0);
      acc[1][nt] = __builtin_amdgcn_mfma_f32_16x16x32_bf16(a1, bb, acc[1][nt], 0, 0, 0);
    }
  }
  const int r4 = (lane >> 4) * 4;
  #pragma unroll
  for (int rt = 0; rt < 2; rt++)
    #pragma unroll
    for (int r = 0; r < 4; r++) {
      int row = chunk + wr * 32 + rt * 16 + r4 + r;
      if (row < M) {
        #pragma unroll
        for (int nt = 0; nt < NT; nt++)
          Y[(size_t)row * N + wc * CW + nt * 16 + l15] = f2b(acc[rt][nt][r]);
      }
    }
}

// ========== gather node->edge (bf16->bf16): dst[e] = (1/deg_e) * sum src[v] ==========
template<int F>
__global__ __launch_bounds__(256) void gather_n2e(const int* __restrict__ off, const int* __restrict__ col,
                                                  const u16* __restrict__ src, u16* __restrict__ dst,
                                                  int nrows) {
  const int row = blockIdx.x * 4 + (threadIdx.x >> 6);
  if (row >= nrows) return;
  const int lane = threadIdx.x & 63;
  const int s0 = off[row], s1 = off[row + 1];
  float a0[4] = {}, a1[4] = {};
  int k = s0;
  for (; k + 15 < s1; k += 16) {                    // 16 outstanding row loads
    int ii[16];
    #pragma unroll
    for (int t = 0; t < 16; t++) ii[t] = col[k + t];
    if constexpr (F == 128) {
      ushort2 uu[16];
      #pragma unroll
      for (int t = 0; t < 16; t++) uu[t] = *(const ushort2*)(src + (size_t)ii[t] * F + lane * 2);
      #pragma unroll
      for (int t = 0; t < 16; t++) { a0[t & 3] += b2f(uu[t].x); a1[t & 3] += b2f(uu[t].y); }
    } else {
      u16 uu[16];
      #pragma unroll
      for (int t = 0; t < 16; t++) uu[t] = src[(size_t)ii[t] * F + lane];
      #pragma unroll
      for (int t = 0; t < 16; t++) a0[t & 3] += b2f(uu[t]);
    }
  }
  for (; k + 3 < s1; k += 4) {
    int ii[4];
    #pragma unroll
    for (int t = 0; t < 4; t++) ii[t] = col[k + t];
    if constexpr (F == 128) {
      ushort2 uu[4];
      #pragma unroll
      for (int t = 0; t < 4; t++) uu[t] = *(const ushort2*)(src + (size_t)ii[t] * F + lane * 2);
      #pragma unroll
      for (int t = 0; t < 4; t++) { a0[t] += b2f(uu[t].x); a1[t] += b2f(uu[t].y); }
    } else {
      u16 uu[4];
      #pragma unroll
      for (int t = 0; t < 4; t++) uu[t] = src[(size_t)ii[t] * F + lane];
      #pragma unroll
      for (int t = 0; t < 4; t++) a0[t] += b2f(uu[t]);
    }
  }
  for (; k < s1; k++) {
    int i0 = col[k];
    if constexpr (F == 128) {
      ushort2 u0 = *(const ushort2*)(src + (size_t)i0 * F + lane * 2);
      a0[0] += b2f(u0.x); a1[0] += b2f(u0.y);
    } else a0[0] += b2f(src[(size_t)i0 * F + lane]);
  }
  const float sc = (s1 > s0) ? 1.0f / (float)(s1 - s0) : 0.f;
  if constexpr (F == 128) {
    ushort2 o;
    o.x = f2b((a0[0] + a0[1] + a0[2] + a0[3]) * sc);
    o.y = f2b((a1[0] + a1[1] + a1[2] + a1[3]) * sc);
    *(ushort2*)(dst + (size_t)row * F + lane * 2) = o;
  } else {
    dst[(size_t)row * F + lane] = f2b((a0[0] + a0[1] + a0[2] + a0[3]) * sc);
  }
}

// == gather edge->node + bias (+relu): out[v] = [relu]((1/deg_v)*sum src[e] + b); dst bf16 or f32 ==
template<int F, bool RELU, bool DSTBF>
__global__ __launch_bounds__(256) void gather_e2n(const int* __restrict__ off, const int* __restrict__ col,
                                                  const u16* __restrict__ src, const float* __restrict__ bias,
                                                  void* __restrict__ dstv, int nrows) {
  const int row = blockIdx.x * 4 + (threadIdx.x >> 6);
  if (row >= nrows) return;
  const int lane = threadIdx.x & 63;
  const int s0 = off[row], s1 = off[row + 1];
  float a0[4] = {}, a1[4] = {};
  int k = s0;
  for (; k + 15 < s1; k += 16) {
    int ii[16];
    #pragma unroll
    for (int t = 0; t < 16; t++) ii[t] = col[k + t];
    if constexpr (F == 128) {
      ushort2 uu[16];
      #pragma unroll
      for (int t = 0; t < 16; t++) uu[t] = *(const ushort2*)(src + (size_t)ii[t] * F + lane * 2);
      #pragma unroll
      for (int t = 0; t < 16; t++) { a0[t & 3] += b2f(uu[t].x); a1[t & 3] += b2f(uu[t].y); }
    } else {
      u16 uu[16];
      #pragma unroll
      for (int t = 0; t < 16; t++) uu[t] = src[(size_t)ii[t] * F + lane];
      #pragma unroll
      for (int t = 0; t < 16; t++) a0[t & 3] += b2f(uu[t]);
    }
  }
  for (; k + 3 < s1; k += 4) {
    int ii[4];
    #pragma unroll
    for (int t = 0; t < 4; t++) ii[t] = col[k + t];
    if constexpr (F == 128) {
      ushort2 uu[4];
      #pragma unroll
      for (int t = 0; t < 4; t++) uu[t] = *(const ushort2*)(src + (size_t)ii[t] * F + lane * 2);
      #pragma unroll
      for (int t = 0; t < 4; t++) { a0[t] += b2f(uu[t].x); a1[t] += b2f(uu[t].y); }
    } else {
      u16 uu[4];
      #pragma unroll
      for (int t = 0; t < 4; t++) uu[t] = src[(size_t)ii[t] * F + lane];
      #pragma unroll
      for (int t = 0; t < 4; t++) a0[t] += b2f(uu[t]);
    }
  }
  for (; k < s1; k++) {
    int i0 = col[k];
    if constexpr (F == 128) {
      ushort2 u0 = *(const ushort2*)(src + (size_t)i0 * F + lane * 2);
      a0[0] += b2f(u0.x); a1[0] += b2f(u0.y);
    } else a0[0] += b2f(src[(size_t)i0 * F + lane]);
  }
  const float sc = (s1 > s0) ? 1.0f / (float)(s1 - s0) : 0.f;
  if constexpr (F == 128) {
    float v0 = (a0[0] + a0[1] + a0[2] + a0[3]) * sc + bias[lane * 2];
    float v1 = (a1[0] + a1[1] + a1[2] + a1[3]) * sc + bias[lane * 2 + 1];
    if (RELU) { v0 = fmaxf(v0, 0.f); v1 = fmaxf(v1, 0.f); }
    if constexpr (DSTBF) {
      ushort2 o; o.x = f2b(v0); o.y = f2b(v1);
      *(ushort2*)((u16*)dstv + (size_t)row * F + lane * 2) = o;
    } else {
      *(float2*)((float*)dstv + (size_t)row * F + lane * 2) = make_float2(v0, v1);
    }
  } else {
    float v0 = (a0[0] + a0[1] + a0[2] + a0[3]) * sc + bias[lane];
    if (RELU) v0 = fmaxf(v0, 0.f);
    if constexpr (DSTBF) ((u16*)dstv)[(size_t)row * F + lane] = f2b(v0);
    else ((float*)dstv)[(size_t)row * F + lane] = v0;
  }
}

extern "C" void kernel_launch(void* const* d_in, const int* in_sizes, int n_in,
                              void* d_out, int out_size, void* d_ws, size_t ws_size,
                              hipStream_t stream) {
  const float* x  = (const float*)d_in[0];
  const int*   hi = (const int*)d_in[1];
  const float* W1 = (const float*)d_in[2];
  const float* b1 = (const float*)d_in[3];
  const float* W2 = (const float*)d_in[4];
  const float* b2 = (const float*)d_in[5];
  float* out = (float*)d_out;
  const int* nidx = hi;             // row 0: node indices
  const int* eidx = hi + NNZV;      // row 1: edge indices

  char* w = (char*)d_ws;
  int*      off_e = (int*)w;                           // 100001 ints
  int*      off_v = (int*)(w + 524288);                // 100001 ints
  int*      gcnt  = (int*)(w + 1048576);               // 392 ints
  u16*      W1T   = (u16*)(w + 1052672);               // 128x128 bf16
  u16*      W2T   = (u16*)(w + 1085440);               // 64x128 bf16
  int*      col_e = (int*)(w + 2097152);               // 1.6M ints
  int*      col_v = (int*)(w + 8650752);               // 1.6M ints
  unsigned* bk    = (unsigned*)(w + 16777216);         // 2*196*12288*4B = 19.3 MB
  u16*      bufH  = (u16*)(w + 56623104);              // 25.6 MB: h1, then h2, then m2e
  u16*      bufM  = (u16*)(w + 56623104 + 25600000);   // 25.6 MB: m_e, then g2

  // ---- weight pre-transpose + CSR build ----
  hipMemsetAsync(gcnt, 0, 392 * 4, stream);
  wtrans_kernel<<<96, 256, 0, stream>>>(W1, W2, W1T, W2T);
  partition_kernel<<<NTIL2, 256, 0, stream>>>(nidx, eidx, gcnt, bk);
  bucket_sort_kernel<<<2 * NBK, 512, 0, stream>>>(gcnt, bk, off_e, off_v, col_e, col_v);

  // ---- conv1 (F=128) ----
  gemm_kernel<128, false><<<1563, 256, 0, stream>>>(x, W1T, bufH, NODES);          // h1(bf16)
  gather_n2e<128><<<(EDGES + 3) / 4, 256, 0, stream>>>(off_e, col_e, bufH, bufM, EDGES);   // m_e
  gather_e2n<128, true, true><<<(NODES + 3) / 4, 256, 0, stream>>>(off_v, col_v, bufM, b1, bufH, NODES); // h2

  // ---- conv2 (F=64) ----
  gemm_kernel<64, true><<<1563, 256, 0, stream>>>(bufH, W2T, bufM, NODES);         // g2(bf16)
  gather_n2e<64><<<(EDGES + 3) / 4, 256, 0, stream>>>(off_e, col_e, bufM, bufH, EDGES);    // m2e
  gather_e2n<64, false, false><<<(NODES + 3) / 4, 256, 0, stream>>>(off_v, col_v, bufH, b2, out, NODES);
}

// Round 8
// 316.235 us; speedup vs baseline: 2.6528x; 1.0838x over previous
//
#include <hip/hip_runtime.h>

#define NODES 100000
#define EDGES 100000
#define NNZV  1600000
#define NBK   196          // buckets per direction (512 rows each)
#define BKCAP 12288        // entry capacity per bucket (mean 8192)
#define TILE2 2048         // entries per partition block (256 thr x 8, both dirs)
#define NTIL2 782          // ceil(NNZV / TILE2)

typedef unsigned short u16;
typedef __attribute__((ext_vector_type(8))) short bf16x8;   // 8 bf16 (4 VGPRs)
typedef __attribute__((ext_vector_type(4))) float f32x4;

__device__ __forceinline__ float b2f(u16 h) {
  union { unsigned u; float f; } c; c.u = ((unsigned)h) << 16; return c.f;
}
__device__ __forceinline__ u16 f2b(float f) {
  union { unsigned u; float f; } c; c.f = f;
  unsigned u = c.u + 0x7FFF + ((c.u >> 16) & 1);   // round-to-nearest-even
  return (u16)(u >> 16);
}

// ============ W pre-transpose: W1T[n][128] = bf16(W1[k][n]), same for W2 ============
__global__ __launch_bounds__(256) void wtrans_kernel(const float* __restrict__ W1,
                                                     const float* __restrict__ W2,
                                                     u16* __restrict__ W1T, u16* __restrict__ W2T) {
  int i = blockIdx.x * 256 + threadIdx.x;
  if (i < 16384) {
    int k = i >> 7, n = i & 127;
    W1T[n * 128 + k] = f2b(W1[i]);
  } else if (i < 16384 + 8192) {
    int j = i - 16384;
    int k = j >> 6, n = j & 63;
    W2T[n * 128 + k] = f2b(W2[j]);
  }
}

// ====== K1: single-pass dual-direction partition into 2x196 row-range buckets ======
__global__ __launch_bounds__(256) void partition_kernel(const int* __restrict__ nidx,
                                                        const int* __restrict__ eidx,
                                                        int* __restrict__ gcnt,
                                                        unsigned* __restrict__ bk) {
  __shared__ int lcnt_e[NBK], lcnt_n[NBK], lbase_e[NBK], lbase_n[NBK];
  const int tid = threadIdx.x;
  const int j0 = blockIdx.x * TILE2;
  for (int i = tid; i < NBK; i += 256) { lcnt_e[i] = 0; lcnt_n[i] = 0; }
  __syncthreads();
  int be[8], bn[8]; unsigned pe[8], pn[8];
  #pragma unroll
  for (int i = 0; i < 8; i++) {
    int j = j0 + tid + i * 256;
    if (j < NNZV) {
      int e = __builtin_nontemporal_load(eidx + j);
      int n = __builtin_nontemporal_load(nidx + j);
      be[i] = e >> 9; pe[i] = ((unsigned)(e & 511) << 17) | (unsigned)n;
      bn[i] = n >> 9; pn[i] = ((unsigned)(n & 511) << 17) | (unsigned)e;
      atomicAdd(&lcnt_e[be[i]], 1);
      atomicAdd(&lcnt_n[bn[i]], 1);
    } else { be[i] = -1; bn[i] = -1; }
  }
  __syncthreads();
  for (int b = tid; b < NBK; b += 256) {
    int c = lcnt_e[b];
    lbase_e[b] = c ? atomicAdd(&gcnt[b], c) : 0;
    lcnt_e[b] = 0;
    c = lcnt_n[b];
    lbase_n[b] = c ? atomicAdd(&gcnt[NBK + b], c) : 0;
    lcnt_n[b] = 0;
  }
  __syncthreads();
  #pragma unroll
  for (int i = 0; i < 8; i++) {
    if (be[i] >= 0) {
      int p = lbase_e[be[i]] + atomicAdd(&lcnt_e[be[i]], 1);
      if (p < BKCAP) bk[(size_t)be[i] * BKCAP + p] = pe[i];
      p = lbase_n[bn[i]] + atomicAdd(&lcnt_n[bn[i]], 1);
      if (p < BKCAP) bk[(size_t)(NBK + bn[i]) * BKCAP + p] = pn[i];
    }
  }
}

// ===== K2: per-bucket counting sort -> off[] + col[]; scatter stays in hot L2 =====
__global__ __launch_bounds__(512) void bucket_sort_kernel(const int* __restrict__ gcnt,
                                                          const unsigned* __restrict__ bk,
                                                          int* __restrict__ off_e, int* __restrict__ off_v,
                                                          int* __restrict__ col_e, int* __restrict__ col_v) {
  const int gb = blockIdx.x;                       // 0..2*NBK-1
  const int dir = gb >= NBK ? 1 : 0;
  const int b = dir ? gb - NBK : gb;
  const int* __restrict__ cnt = gcnt + dir * NBK;
  const unsigned* __restrict__ bkd = bk + ((size_t)dir * NBK + b) * BKCAP;
  int* __restrict__ off = dir ? off_v : off_e;
  int* __restrict__ col = dir ? col_v : col_e;
  const int tid = threadIdx.x, lane = tid & 63, wid = tid >> 6;
  __shared__ int lcnt[512];
  __shared__ int wsum[8];
  __shared__ int base_s;
  if (tid < 64) {                                   // base = sum cnt[0..b)
    int s = 0;
    for (int t = tid; t < b; t += 64) s += cnt[t];
    #pragma unroll
    for (int d = 1; d < 64; d <<= 1) s += __shfl_xor(s, d);
    if (tid == 0) base_s = s;
  }
  lcnt[tid] = 0;
  __syncthreads();
  const int n = min(cnt[b], BKCAP);
  for (int i = tid; i < n; i += 512)
    atomicAdd(&lcnt[bkd[i] >> 17], 1);
  __syncthreads();
  int x = lcnt[tid];                                // per-row count
  int inc = x;
  #pragma unroll
  for (int d = 1; d < 64; d <<= 1) { int t = __shfl_up(inc, d); if (lane >= d) inc += t; }
  if (lane == 63) wsum[wid] = inc;
  __syncthreads();
  int wbase = 0;
  for (int k = 0; k < wid; k++) wbase += wsum[k];
  const int gpos = base_s + wbase + inc - x;        // global exclusive position for row tid
  const int row = (b << 9) + tid;
  if (row < NODES) off[row] = gpos;
  if (b == NBK - 1 && tid == 0) off[NODES] = NNZV;
  __syncthreads();
  lcnt[tid] = gpos;                                 // cursor = global position
  __syncthreads();
  for (int i = tid; i < n; i += 512) {
    unsigned e = bkd[i];
    int p = atomicAdd(&lcnt[e >> 17], 1);
    col[p] = (int)(e & 0x1FFFFu);
  }
}

// ======= MFMA GEMM: Y[M,N](bf16) = X[M,128] @ W[128,N]; WT is pre-transposed bf16 [N][128] =======
template<int N, bool XBF>
__global__ __launch_bounds__(256) void gemm_kernel(const void* __restrict__ Xv,
                                                   const u16* __restrict__ WT,
                                                   u16* __restrict__ Y, int M) {
  __shared__ u16 sX[64 * 136];
  __shared__ u16 sW[N * 136];
  const int tid = threadIdx.x, lane = tid & 63, w = tid >> 6;
  const int chunk = blockIdx.x * 64;
  constexpr int WV = N * 128 / 8;
  for (int t = tid; t < WV; t += 256) {
    int e = t * 8, n = e >> 7, k = e & 127;
    *(bf16x8*)(sW + n * 136 + k) = *(const bf16x8*)(WT + n * 128 + k);
  }
  if constexpr (XBF) {
    const u16* X = (const u16*)Xv;
    for (int t = tid; t < 1024; t += 256) {
      int e = t * 8, r = e >> 7, k = e & 127;
      int row = min(chunk + r, M - 1);
      *(bf16x8*)(sX + r * 136 + k) = *(const bf16x8*)(X + (size_t)row * 128 + k);
    }
  } else {
    const float* X = (const float*)Xv;
    for (int t = tid; t < 2048; t += 256) {
      int r = t >> 5, c4 = t & 31;
      int row = min(chunk + r, M - 1);
      float4 v = *(const float4*)(X + (size_t)row * 128 + c4 * 4);
      ushort4 o = { f2b(v.x), f2b(v.y), f2b(v.z), f2b(v.w) };
      *(ushort4*)(sX + r * 136 + c4 * 4) = o;
    }
  }
  __syncthreads();
  constexpr int CW = N / 2;
  constexpr int NT = CW / 16;
  const int wr = w >> 1, wc = w & 1;
  const int l15 = lane & 15;
  const int arow = wr * 32 + l15;
  const int kb = (lane >> 4) * 8;
  f32x4 acc[2][NT];
  #pragma unroll
  for (int rt = 0; rt < 2; rt++)
    #pragma unroll
    for (int nt = 0; nt < NT; nt++) acc[rt][nt] = (f32x4){0.f, 0.f, 0.f, 0.f};
  #pragma unroll
  for (int kk = 0; kk < 4; kk++) {
    const int ko = kk * 32 + kb;
    bf16x8 a0 = *(const bf16x8*)(sX + arow * 136 + ko);
    bf16x8 a1 = *(const bf16x8*)(sX + (arow + 16) * 136 + ko);
    #pragma unroll
    for (int nt = 0; nt < NT; nt++) {
      bf16x8 bb = *(const bf16x8*)(sW + (wc * CW + nt * 16 + l15) * 136 + ko);
      acc[0][nt] = __builtin_amdgcn_mfma_f32_16x16x32_bf16(a0, bb, acc[0][nt], 0, 0, 0);
      acc[1][nt] = __builtin_amdgcn_mfma_f32_16x16x32_bf16(a1, bb, acc[1][nt], 0, 0, 0);
    }
  }
  const int r4 = (lane >> 4) * 4;
  #pragma unroll
  for (int rt = 0; rt < 2; rt++)
    #pragma unroll
    for (int r = 0; r < 4; r++) {
      int row = chunk + wr * 32 + rt * 16 + r4 + r;
      if (row < M) {
        #pragma unroll
        for (int nt = 0; nt < NT; nt++)
          Y[(size_t)row * N + wc * CW + nt * 16 + l15] = f2b(acc[rt][nt][r]);
      }
    }
}

// ===== member-parallel gather: wave = 1 dst row; lane = (member-slot g, feature-block l) =====
// One VMEM instr loads G members' 16B sub-rows (G=4 @F=128, G=8 @F=64).
// dst[row] = (1/deg) * sum_{c in members} src[c]  [+ bias] [relu]; dst bf16 or f32.
template<int F, bool HASB, bool RELU, bool DSTBF>
__global__ __launch_bounds__(256) void gather_kernel(const int* __restrict__ off,
                                                     const int* __restrict__ col,
                                                     const u16* __restrict__ src,
                                                     const float* __restrict__ bias,
                                                     void* __restrict__ dstv, int nrows) {
  constexpr int G = (F == 128) ? 4 : 8;   // member slots per wave
  constexpr int L = 64 / G;               // lanes per member (L*8 = F feats)
  const int row = blockIdx.x * 4 + (threadIdx.x >> 6);
  if (row >= nrows) return;
  const int lane = threadIdx.x & 63;
  const int g = lane / L;                 // member slot
  const int l = lane % L;                 // feature block (8 feats)
  const int s0 = off[row], s1 = off[row + 1];
  float acc[8] = {};
  int k = s0;
  for (; k + 4 * G <= s1; k += 4 * G) {   // 4 big loads in flight (16/32 members)
    int c0 = col[k + g];
    int c1 = col[k + G + g];
    int c2 = col[k + 2 * G + g];
    int c3 = col[k + 3 * G + g];
    bf16x8 v0 = *(const bf16x8*)(src + (size_t)c0 * F + l * 8);
    bf16x8 v1 = *(const bf16x8*)(src + (size_t)c1 * F + l * 8);
    bf16x8 v2 = *(const bf16x8*)(src + (size_t)c2 * F + l * 8);
    bf16x8 v3 = *(const bf16x8*)(src + (size_t)c3 * F + l * 8);
    #pragma unroll
    for (int t = 0; t < 8; t++) acc[t] += b2f((u16)v0[t]);
    #pragma unroll
    for (int t = 0; t < 8; t++) acc[t] += b2f((u16)v1[t]);
    #pragma unroll
    for (int t = 0; t < 8; t++) acc[t] += b2f((u16)v2[t]);
    #pragma unroll
    for (int t = 0; t < 8; t++) acc[t] += b2f((u16)v3[t]);
  }
  for (; k < s1; k += G) {
    int idx = k + g;
    int c = col[min(idx, s1 - 1)];
    bf16x8 v = *(const bf16x8*)(src + (size_t)c * F + l * 8);
    if (idx < s1) {
      #pragma unroll
      for (int t = 0; t < 8; t++) acc[t] += b2f((u16)v[t]);
    }
  }
  // reduce across member slots (feature block l preserved under xor of multiples of L)
  #pragma unroll
  for (int d = L; d < 64; d <<= 1) {
    #pragma unroll
    for (int t = 0; t < 8; t++) acc[t] += __shfl_xor(acc[t], d);
  }
  if (g == 0) {
    const float sc = (s1 > s0) ? 1.0f / (float)(s1 - s0) : 0.f;
    float v[8];
    #pragma unroll
    for (int t = 0; t < 8; t++) {
      v[t] = acc[t] * sc;
      if constexpr (HASB) v[t] += bias[l * 8 + t];
      if constexpr (RELU) v[t] = fmaxf(v[t], 0.f);
    }
    if constexpr (DSTBF) {
      bf16x8 o;
      #pragma unroll
      for (int t = 0; t < 8; t++) o[t] = (short)f2b(v[t]);
      *(bf16x8*)((u16*)dstv + (size_t)row * F + l * 8) = o;
    } else {
      float* d = (float*)dstv + (size_t)row * F + l * 8;
      *(float4*)d = make_float4(v[0], v[1], v[2], v[3]);
      *(float4*)(d + 4) = make_float4(v[4], v[5], v[6], v[7]);
    }
  }
}

extern "C" void kernel_launch(void* const* d_in, const int* in_sizes, int n_in,
                              void* d_out, int out_size, void* d_ws, size_t ws_size,
                              hipStream_t stream) {
  const float* x  = (const float*)d_in[0];
  const int*   hi = (const int*)d_in[1];
  const float* W1 = (const float*)d_in[2];
  const float* b1 = (const float*)d_in[3];
  const float* W2 = (const float*)d_in[4];
  const float* b2 = (const float*)d_in[5];
  float* out = (float*)d_out;
  const int* nidx = hi;             // row 0: node indices
  const int* eidx = hi + NNZV;      // row 1: edge indices

  char* w = (char*)d_ws;
  int*      off_e = (int*)w;                           // 100001 ints
  int*      off_v = (int*)(w + 524288);                // 100001 ints
  int*      gcnt  = (int*)(w + 1048576);               // 392 ints
  u16*      W1T   = (u16*)(w + 1052672);               // 128x128 bf16
  u16*      W2T   = (u16*)(w + 1085440);               // 64x128 bf16
  int*      col_e = (int*)(w + 2097152);               // 1.6M ints
  int*      col_v = (int*)(w + 8650752);               // 1.6M ints
  unsigned* bk    = (unsigned*)(w + 16777216);         // 2*196*12288*4B = 19.3 MB
  u16*      bufH  = (u16*)(w + 56623104);              // 25.6 MB: h1, then h2, then m2e
  u16*      bufM  = (u16*)(w + 56623104 + 25600000);   // 25.6 MB: m_e, then g2

  // ---- weight pre-transpose + CSR build ----
  hipMemsetAsync(gcnt, 0, 392 * 4, stream);
  wtrans_kernel<<<96, 256, 0, stream>>>(W1, W2, W1T, W2T);
  partition_kernel<<<NTIL2, 256, 0, stream>>>(nidx, eidx, gcnt, bk);
  bucket_sort_kernel<<<2 * NBK, 512, 0, stream>>>(gcnt, bk, off_e, off_v, col_e, col_v);

  // ---- conv1 (F=128) ----
  gemm_kernel<128, false><<<1563, 256, 0, stream>>>(x, W1T, bufH, NODES);          // h1(bf16)
  gather_kernel<128, false, false, true><<<(EDGES + 3) / 4, 256, 0, stream>>>(
      off_e, col_e, bufH, nullptr, bufM, EDGES);                                   // m_e
  gather_kernel<128, true, true, true><<<(NODES + 3) / 4, 256, 0, stream>>>(
      off_v, col_v, bufM, b1, bufH, NODES);                                        // h2
  // ---- conv2 (F=64) ----
  gemm_kernel<64, true><<<1563, 256, 0, stream>>>(bufH, W2T, bufM, NODES);         // g2(bf16)
  gather_kernel<64, false, false, true><<<(EDGES + 3) / 4, 256, 0, stream>>>(
      off_e, col_e, bufM, nullptr, bufH, EDGES);                                   // m2e
  gather_kernel<64, true, false, false><<<(NODES + 3) / 4, 256, 0, stream>>>(
      off_v, col_v, bufH, b2, out, NODES);                                         // out(f32)
}